// Round 7
// baseline (114.275 us; speedup 1.0000x reference)
//
#include <hip/hip_runtime.h>
#include <hip/hip_bf16.h>

#define FEAT   256
#define TROWS  16
#define TBYTES (TROWS * FEAT * 4)   // 16 KiB per x-tile
#define NBUF   3                    // depth-3: loads lead compute by 2 tiles

typedef __attribute__((ext_vector_type(8))) short  short8;
typedef __attribute__((ext_vector_type(4))) float  floatx4;

__device__ __forceinline__ short f2bf(float f) {
    __hip_bfloat16 h = __float2bfloat16(f);   // RTNE; pairs fuse to v_cvt_pk_bf16_f32
    return __builtin_bit_cast(short, h);
}

// Byte-offset swizzle within a 16-row x-tile: XOR bits 4..6 with row&7
// (row = offset>>10). Involution, 16 B-granular. Applied to the gload_lds
// SOURCE (dest linear, per HW) and to every LDS READ.
__device__ __forceinline__ unsigned swz(unsigned o) {
    return o ^ (((o >> 10) & 7u) << 4);
}

// R6 + two fixes:
// (1) SWAPPED MFMA operands: acc = mfma(A=gamma-frag, B=x2-frag) computes
//     D[i=gamma-col, j=x-row]; C/D layout (col=lane&15=j, row=grp*4+reg=i)
//     => lane l15 holds x-row, regs r hold 4 CONSECUTIVE output columns
//     (colbase + nt*16 + grp*4 + r). Epilogue: 4 ds_read_b128 + 4
//     global_store_dwordx4 per wave (was 16 ds_read_b32 + 16 store_dword).
//     k_A==k_B verified on HW: R1 passed with gamma=0.1*I + random x.
// (2) STORE-AWARE counted vmcnt: stores count in vmcnt. Per iter: 4 loads +
//     4 stores. At the wait point (after STAGE(it+2)) ops newer than L(it):
//     S(it-2) 4 + L(it+1) 4 + S(it-1) 4 + L(it+2) 4 = 16 -> vmcnt(16)
//     (it=0: 8, it=1: 12). R6's vmcnt(8) was silently draining 24 stores/iter.
__global__ __launch_bounds__(256, 2) void gdn_kernel(
    const float* __restrict__ x,
    const float* __restrict__ beta,
    const float* __restrict__ gamma,
    float* __restrict__ out,
    int batch)
{
    __shared__ char ldsx[NBUF * TBYTES];   // 48 KiB -> 2 blocks/CU

    const int tid  = threadIdx.x;
    const int lane = tid & 63;
    const int wave = tid >> 6;          // 0..3 -> 64-col slice
    const int l15  = lane & 15;
    const int grp  = lane >> 4;
    const int colbase = wave * 64;

    // ---- One-time: gamma fragments as bf16, 128 regs (unified VGPR/AGPR).
    // k-hat map k = ks*32 + grp*8 + i, identical for both operands.
    short8 Bf[4][8];
    #pragma unroll
    for (int nt = 0; nt < 4; ++nt) {
        const int col = colbase + nt * 16 + l15;
        #pragma unroll
        for (int ks = 0; ks < 8; ++ks) {
            const int k0 = ks * 32 + grp * 8;
            short8 b;
            #pragma unroll
            for (int i = 0; i < 8; ++i)
                b[i] = f2bf(gamma[(size_t)(k0 + i) * FEAT + col]);
            Bf[nt][ks] = b;
        }
    }

    // beta_c per (nt, reg): cols colbase + nt*16 + grp*4 + r
    floatx4 bc4[4];
    #pragma unroll
    for (int nt = 0; nt < 4; ++nt) {
        floatx4 b = *(const floatx4*)(beta + colbase + nt * 16 + grp * 4);
        #pragma unroll
        for (int r = 0; r < 4; ++r) bc4[nt][r] = fmaxf(b[r], 1e-6f);
    }

    const int ntiles = batch >> 4;      // 16384
    const int stride = gridDim.x;       // 512 -> exactly 32 iters/block
    const int iters  = ntiles / stride; // 32 (exact)
    const int t0     = blockIdx.x;

    // Async stage of tile `t` into LDS slot `s`: dest LINEAR (wave-uniform
    // base + lane*16), source pre-swizzled with the read involution.
    auto STAGE = [&](int s, int t) {
        const char* gb = (const char*)x + (size_t)t * TBYTES;
        char* lbase = &ldsx[s * TBYTES];
        #pragma unroll
        for (int r = 0; r < 4; ++r) {
            const unsigned d = (unsigned)(tid * 16 + r * 4096);
            __builtin_amdgcn_global_load_lds(
                (const __attribute__((address_space(1))) void*)(gb + swz(d)),
                (__attribute__((address_space(3))) void*)(lbase + d),
                16, 0, 0);
        }
    };

    // Prologue: 2 tiles in flight before first compute.
    STAGE(0, t0);
    STAGE(1, t0 + stride);

    for (int it = 0; it < iters; ++it) {
        // Barrier A: every wave finished READING slot (it+2)%3 (at iter it-1).
        __builtin_amdgcn_s_barrier();
        __builtin_amdgcn_sched_barrier(0);

        int itn = it + 2;
        if (itn >= iters) itn = iters - 1;          // redundant tail re-stage
        STAGE((it + 2) % NBUF, t0 + itn * stride);  // slot-safe; never read

        // Wait ONLY for tile-it loads (in-order vmcnt); newer loads AND all
        // recent stores stay in flight.
        if (it == 0)      asm volatile("s_waitcnt vmcnt(8)"  ::: "memory");
        else if (it == 1) asm volatile("s_waitcnt vmcnt(12)" ::: "memory");
        else              asm volatile("s_waitcnt vmcnt(16)" ::: "memory");
        __builtin_amdgcn_sched_barrier(0);
        // Barrier B: all waves passed the wait -> tile-it fully in LDS.
        __builtin_amdgcn_s_barrier();
        __builtin_amdgcn_sched_barrier(0);

        const char* lb = &ldsx[(it % NBUF) * TBYTES];

        // ---- A-side data (x^2, used as MFMA *B* operand): row l15,
        // floats [ks*32 + grp*8, +8), swizzled read.
        const unsigned p0 = (unsigned)(l15 * 1024 + grp * 32);
        const unsigned xv = (unsigned)((l15 & 7) << 4);
        short8 Af[8];
        #pragma unroll
        for (int ks = 0; ks < 8; ++ks) {
            floatx4 v0 = *(const floatx4*)(lb + ((p0 + ks * 128)      ^ xv));
            floatx4 v1 = *(const floatx4*)(lb + ((p0 + ks * 128 + 16) ^ xv));
            short8 a;
            #pragma unroll
            for (int i = 0; i < 4; ++i) {
                a[i]     = f2bf(v0[i] * v0[i]);
                a[4 + i] = f2bf(v1[i] * v1[i]);
            }
            Af[ks] = a;
        }

        // ---- MFMA over K=256, SWAPPED: D = gamma^T . (x^2)^T
        floatx4 acc[4] = {{0.f,0.f,0.f,0.f},{0.f,0.f,0.f,0.f},
                          {0.f,0.f,0.f,0.f},{0.f,0.f,0.f,0.f}};
        #pragma unroll
        for (int ks = 0; ks < 8; ++ks) {
            #pragma unroll
            for (int nt = 0; nt < 4; ++nt) {
                acc[nt] = __builtin_amdgcn_mfma_f32_16x16x32_bf16(
                    Bf[nt][ks], Af[ks], acc[nt], 0, 0, 0);
            }
        }

        // ---- Epilogue: y = x * rsqrt(acc + beta_c), all 16B-vector.
        // Lane: x-row = l15; 4 consecutive cols = colbase + nt*16 + grp*4 + r.
        const int rb = (t0 + it * stride) << 4;
        float* orow = out + (size_t)(rb + l15) * FEAT + colbase + grp * 4;
        #pragma unroll
        for (int nt = 0; nt < 4; ++nt) {
            const unsigned eo = (unsigned)(l15 * 1024 + (colbase + nt * 16 + grp * 4) * 4);
            floatx4 xval = *(const floatx4*)(lb + (eo ^ xv));
            floatx4 y;
            #pragma unroll
            for (int r = 0; r < 4; ++r)
                y[r] = xval[r] * rsqrtf(acc[nt][r] + bc4[nt][r]);
            *(floatx4*)(orow + nt * 16) = y;
        }
        // no drain: next iter's Barrier A needs only reg-held LDS reads done.
    }
}

extern "C" void kernel_launch(void* const* d_in, const int* in_sizes, int n_in,
                              void* d_out, int out_size, void* d_ws, size_t ws_size,
                              hipStream_t stream) {
    const float* x     = (const float*)d_in[0];
    const float* beta  = (const float*)d_in[1];
    const float* gamma = (const float*)d_in[2];
    float* out = (float*)d_out;

    const int batch = in_sizes[0] / FEAT;   // 262144

    dim3 grid(512);     // 2 blocks/CU, exactly 32 tiles each
    dim3 block(256);    // 4 waves: col-split within block
    hipLaunchKernelGGL(gdn_kernel, grid, block, 0, stream,
                       x, beta, gamma, out, batch);
}